// Round 7
// baseline (453.973 us; speedup 1.0000x reference)
//
#include <hip/hip_runtime.h>

#define BATCHN 2
#define SEQL   2048
#define DM     1024
#define DI     2048
#define DSN    16
#define MTOT   (BATCHN * SEQL)   // 4096
#define PADL   (SEQL + 3)        // 2051
#define NC     64                // scan chunks
#define CL     (SEQL / NC)       // 32
#define BCKS   8                 // bc split-K factor

typedef __attribute__((ext_vector_type(8))) __bf16 bf16x8;
typedef __attribute__((ext_vector_type(4))) float f32x4;

__device__ __forceinline__ unsigned short f2b(float f) {
    union { float f; unsigned u; } v; v.f = f;
    unsigned r = v.u + 0x7FFF + ((v.u >> 16) & 1);
    return (unsigned short)(r >> 16);
}
__device__ __forceinline__ float b2f(unsigned short b) {
    union { float f; unsigned u; } v; v.u = ((unsigned)b) << 16;
    return v.f;
}

__device__ __forceinline__ void gl_lds16(const void* g, void* l) {
    __builtin_amdgcn_global_load_lds(
        (const __attribute__((address_space(1))) unsigned int*)g,
        (__attribute__((address_space(3))) unsigned int*)l, 16, 0, 0);
}

// XCD-aware block swizzle: 8 XCDs arranged 2 (x) x 4 (y) over the tile grid;
// each XCD covers a contiguous rectangle. Requires gx%2==0, gy%4==0.
__device__ __forceinline__ void swz(int& bx, int& by) {
    int gx = gridDim.x, gy = gridDim.y;
    int lin = blockIdx.y * gx + blockIdx.x;
    int xcd = lin & 7, k = lin >> 3;
    int rw = gx >> 1, rh = gy >> 2;
    by = (xcd >> 1) * rh + k / rw;
    bx = (xcd & 1) * rw + k % rw;
}

// ---------------- single merged convert kernel ----------------
#define NB_CW4  (DI * DI / 4 / 256)        // 4096
#define NB_TP   ((DM / 32) * (DI / 32))    // 2048
#define NB_IPZ  (DI * DM / 4 / 256)        // 2048
#define NB_DTW  (DI * DI / 4 / 256)        // 4096
#define NB_OW   (DM * DI / 4 / 256)        // 2048
#define NB_BW   (DSN * DI / 4 / 256 + 1)   // 33
#define NB_XCVT (MTOT * DM / 4 / 256)      // 4096
#define NB_XZ   ((BATCHN * 3 * DM + 255) / 256)  // 24
#define NB_CVT_ALL (NB_CW4 + NB_TP + NB_IPZ + NB_DTW + NB_OW + 2 * NB_BW + NB_XCVT + NB_XZ)

__global__ void __launch_bounds__(256)
cvt_all(const float* __restrict__ x, const float* __restrict__ convw,
        const float* __restrict__ ipw, const float* __restrict__ dtw,
        const float* __restrict__ ow, const float* __restrict__ bw,
        const float* __restrict__ cw,
        unsigned short* __restrict__ xpad, unsigned short* __restrict__ wk,
        unsigned short* __restrict__ Pt, unsigned short* __restrict__ ipz,
        unsigned short* __restrict__ dtwb, unsigned short* __restrict__ owb,
        unsigned short* __restrict__ bcb)
{
    __shared__ float tile[32][33];
    int blk = blockIdx.x;
    int t = threadIdx.x;
    if (blk < NB_CW4) {
        int g = blk * 256 + t;                // ushort4 slot in each plane
        int i = g * 4;                        // float4 index into convw
        const float4* cw4 = (const float4*)convw;
        float4 v0 = cw4[i + 0], v1 = cw4[i + 1], v2 = cw4[i + 2], v3 = cw4[i + 3];
#pragma unroll
        for (int k = 0; k < 4; ++k) {
            float e0 = (&v0.x)[k], e1 = (&v1.x)[k], e2 = (&v2.x)[k], e3 = (&v3.x)[k];
            ushort4 o;
            o.x = f2b(e0); o.y = f2b(e1); o.z = f2b(e2); o.w = f2b(e3);
            ((ushort4*)(wk + (size_t)k * DI * DI))[g] = o;
        }
        return;
    }
    blk -= NB_CW4;
    if (blk < NB_TP) {
        int ct = (blk & 31) * 32, it = (blk >> 5) * 32;
        int tx = t & 31, ty = t >> 5;   // 32 x 8
#pragma unroll
        for (int r = 0; r < 4; ++r)
            tile[ty + r * 8][tx] = ipw[(size_t)(it + ty + r * 8) * DM + ct + tx];
        __syncthreads();
#pragma unroll
        for (int r = 0; r < 4; ++r)
            Pt[(size_t)(ct + ty + r * 8) * DI + it + tx] = f2b(tile[tx][ty + r * 8]);
        return;
    }
    blk -= NB_TP;
    if (blk < NB_IPZ + NB_DTW + NB_OW + 2 * NB_BW) {
        const float* src;
        unsigned short* dst;
        int n4;
        if (blk < NB_IPZ) {
            src = ipw + (size_t)DI * DM; dst = ipz; n4 = DI * DM / 4;
        } else if ((blk -= NB_IPZ) < NB_DTW) {
            src = dtw; dst = dtwb; n4 = DI * DI / 4;
        } else if ((blk -= NB_DTW) < NB_OW) {
            src = ow; dst = owb; n4 = DM * DI / 4;
        } else if ((blk -= NB_OW) < NB_BW) {
            src = bw; dst = bcb; n4 = DSN * DI / 4;
        } else {
            blk -= NB_BW;
            src = cw; dst = bcb + (size_t)DSN * DI; n4 = DSN * DI / 4;
        }
        int i = blk * 256 + t;
        if (i < n4) {
            float4 v = ((const float4*)src)[i];
            ushort4 o;
            o.x = f2b(v.x); o.y = f2b(v.y); o.z = f2b(v.z); o.w = f2b(v.w);
            ((ushort4*)dst)[i] = o;
        }
        return;
    }
    blk -= NB_IPZ + NB_DTW + NB_OW + 2 * NB_BW;
    if (blk < NB_XCVT) {
        int i = blk * 256 + t;
        int b = i >> 19;
        float4 v = ((const float4*)x)[i];
        ushort4 o;
        o.x = f2b(v.x); o.y = f2b(v.y); o.z = f2b(v.z); o.w = f2b(v.w);
        ((ushort4*)xpad)[i + (b + 1) * (3 * DM / 4)] = o;
        return;
    }
    blk -= NB_XCVT;
    {
        int i = blk * 256 + t;
        if (i < BATCHN * 3 * DM) {
            int b = i / (3 * DM);
            int r = i % (3 * DM);
            xpad[(size_t)b * PADL * DM + r] = 0;
        }
    }
}

// ---------------- legacy 128x128 MFMA GEMM (kept for MODE 3 = out-proj) ----
template<int MODE>
__global__ void __launch_bounds__(256)
gemm_bt(const unsigned short* __restrict__ Abase,
        const unsigned short* __restrict__ Bbase,
        const float* __restrict__ bias,
        unsigned short* __restrict__ out_bf,
        float* __restrict__ out_f,
        int K)
{
    __shared__ __align__(16) unsigned short As[128 * 64];
    __shared__ __align__(16) unsigned short Bs[128 * 64];

    const int t = threadIdx.x;
    const int lane = t & 63;
    const int wave = t >> 6;
    const int wm = wave & 1, wn = wave >> 1;
    int bx, by;
    swz(bx, by);
    const int m0 = by * 128, n0 = bx * 128;
    const int srow = t >> 3;                          // 0..31
    const int scol = (t & 7) * 8;                     // LDS physical col (bf16)
    const int gcol = (((t & 7) ^ (srow & 7))) * 8;    // swizzled global col

    f32x4 acc[4][4];
#pragma unroll
    for (int i = 0; i < 4; ++i)
#pragma unroll
        for (int j = 0; j < 4; ++j)
            acc[i][j] = f32x4{0.f, 0.f, 0.f, 0.f};

    const unsigned short* arow[4];
    const unsigned short* brow[4];
#pragma unroll
    for (int i = 0; i < 4; ++i) {
        int rg = m0 + srow + i * 32;
        arow[i] = Abase + (size_t)rg * K;
        int ng = n0 + srow + i * 32;
        brow[i] = Bbase + (size_t)ng * K;
    }
    for (int k0 = 0; k0 < K; k0 += 64) {
#pragma unroll
        for (int i = 0; i < 4; ++i)
            gl_lds16(arow[i] + k0 + gcol, &As[(size_t)(srow + i * 32) * 64 + scol]);
#pragma unroll
        for (int i = 0; i < 4; ++i)
            gl_lds16(brow[i] + k0 + gcol, &Bs[(size_t)(srow + i * 32) * 64 + scol]);
        __syncthreads();
        const int qa = (lane >> 4) * 8;
        const int am = lane & 15;
        const int sw = (am & 7) << 3;   // XOR swizzle on element col
#pragma unroll
        for (int kk = 0; kk < 64; kk += 32) {
            bf16x8 af[4], bfv[4];
#pragma unroll
            for (int i = 0; i < 4; ++i)
                af[i] = *(const bf16x8*)&As[(wm * 64 + i * 16 + am) * 64 + ((kk + qa) ^ sw)];
#pragma unroll
            for (int j = 0; j < 4; ++j)
                bfv[j] = *(const bf16x8*)&Bs[(wn * 64 + j * 16 + am) * 64 + ((kk + qa) ^ sw)];
#pragma unroll
            for (int i = 0; i < 4; ++i)
#pragma unroll
                for (int j = 0; j < 4; ++j)
                    acc[i][j] = __builtin_amdgcn_mfma_f32_16x16x32_bf16(
                        af[i], bfv[j], acc[i][j], 0, 0, 0);
        }
        __syncthreads();
    }

    const int erow0 = m0 + wm * 64;
    const int ecol0 = n0 + wn * 64 + (lane & 15);
    const int rq = (lane >> 4) * 4;
#pragma unroll
    for (int i = 0; i < 4; ++i) {
#pragma unroll
        for (int j = 0; j < 4; ++j) {
            int col = ecol0 + j * 16;
#pragma unroll
            for (int r = 0; r < 4; ++r) {
                int row = erow0 + i * 16 + rq + r;
                float v = acc[i][j][r];
                if (MODE == 3) {
                    out_f[(size_t)row * DM + col] = v;
                } else {
                    out_bf[(size_t)row * DI + col] = f2b(v);
                }
            }
        }
    }
}

// ---------------- pipelined MFMA GEMM (256x128 tile, 8 waves) -------------
// R2 structure (control; ~946 TF structural ceiling for 64x64/wave geometry).
#define STAGE(buf, kt) do { \
    const int kc_ = ((kt) & NTM) << 6; \
    gl_lds16(pA + 0 * 64 * SA + kc_, &lds[(buf) * 16384 + ldsA + 0 * 4096]); \
    gl_lds16(pA + 1 * 64 * SA + kc_, &lds[(buf) * 16384 + ldsA + 1 * 4096]); \
    gl_lds16(pA + 2 * 64 * SA + kc_, &lds[(buf) * 16384 + ldsA + 2 * 4096]); \
    gl_lds16(pA + 3 * 64 * SA + kc_, &lds[(buf) * 16384 + ldsA + 3 * 4096]); \
    gl_lds16(pB + 0 * 64 * SB + kc_, &lds[32768 + (buf) * 8192 + ldsB + 0 * 4096]); \
    gl_lds16(pB + 1 * 64 * SB + kc_, &lds[32768 + (buf) * 8192 + ldsB + 1 * 4096]); \
} while (0)

#define LOADF(AF, BF, buf) do { \
    const unsigned short* _ab = &lds[(buf) * 16384 + arow]; \
    const unsigned short* _bb = &lds[32768 + (buf) * 8192 + brow]; \
    _Pragma("unroll") \
    for (int _i = 0; _i < 4; ++_i) { \
        AF[_i][0] = *(const bf16x8*)&_ab[_i * 1024 + c0]; \
        AF[_i][1] = *(const bf16x8*)&_ab[_i * 1024 + c1]; \
    } \
    _Pragma("unroll") \
    for (int _j = 0; _j < 4; ++_j) { \
        BF[_j][0] = *(const bf16x8*)&_bb[_j * 1024 + c0]; \
        BF[_j][1] = *(const bf16x8*)&_bb[_j * 1024 + c1]; \
    } \
} while (0)

#define MME(AF, BF) do { \
    _Pragma("unroll") \
    for (int _i = 0; _i < 4; ++_i) \
    _Pragma("unroll") \
    for (int _j = 0; _j < 4; ++_j) { \
        acc[_i][_j] = __builtin_amdgcn_mfma_f32_16x16x32_bf16(AF[_i][0], BF[_j][0], acc[_i][_j], 0, 0, 0); \
        acc[_i][_j] = __builtin_amdgcn_mfma_f32_16x16x32_bf16(AF[_i][1], BF[_j][1], acc[_i][_j], 0, 0, 0); \
    } \
} while (0)

template<int MODE>
__global__ void __launch_bounds__(512, 1)
gemm8(const unsigned short* __restrict__ Abase,
      const unsigned short* __restrict__ Bbase,
      const float* __restrict__ bias,
      unsigned short* __restrict__ out_bf,
      float* __restrict__ out_f)
{
    constexpr int K   = (MODE == 0) ? 1024 : (MODE == 1) ? 4096 : 2048;
    constexpr int SA  = (MODE == 2 || MODE == 4) ? 2048 : 1024;
    constexpr int SB  = (MODE == 0) ? 1024 : (MODE == 1) ? 4096 : 2048;
    constexpr int NT  = K / 64;
    constexpr int NTM = NT - 1;
    constexpr int NI  = NT / 2;
    (void)out_f;

    __shared__ __align__(16) unsigned short lds[49152];   // 96 KiB

    const int t = threadIdx.x;
    const int lane = t & 63;
    const int wave = t >> 6;       // 0..7
    const int wm = wave >> 1;      // 0..3 (M quarters, 64 rows each)
    const int wn = wave & 1;       // 0..1 (N halves, 64 cols each)
    int bx, by;
    swz(bx, by);
    const int m0 = by * 256, n0 = bx * 128;

    const unsigned short* Ap;
    if (MODE == 0)      Ap = Abase + ((size_t)(m0 >> 11) * PADL + 3 + (m0 & 2047)) * DM;
    else if (MODE == 1) Ap = Abase + ((size_t)(m0 >> 11) * PADL + (m0 & 2047)) * DM;
    else if (MODE == 4) Ap = Abase + (size_t)blockIdx.z * DI * DI + (size_t)m0 * SA;
    else                Ap = Abase + (size_t)m0 * SA;
    const unsigned short* Bp = Bbase + (size_t)n0 * SB;

    const int strow = t >> 3;                           // 0..63
    const int gcs = ((t & 7) ^ (strow & 7)) * 8;        // inverse-swizzled src col
    const unsigned short* pA = Ap + (size_t)strow * SA + gcs;
    const unsigned short* pB = Bp + (size_t)strow * SB + gcs;
    const int ldsA = t * 8;
    const int ldsB = t * 8;

    const int am = lane & 15;
    const int qa = (lane >> 4) << 3;
    const int sw = (am & 7) << 3;
    const int c0 = qa ^ sw;
    const int c1 = (32 + qa) ^ sw;
    const int arow = (wm * 64 + am) * 64;
    const int brow = (wn * 64 + am) * 64;

    f32x4 acc[4][4];
#pragma unroll
    for (int i = 0; i < 4; ++i)
#pragma unroll
        for (int j = 0; j < 4; ++j)
            acc[i][j] = f32x4{0.f, 0.f, 0.f, 0.f};

    bf16x8 aX[4][2], bX[4][2], aY[4][2], bY[4][2];

    STAGE(0, 0);
    STAGE(1, 1);
    asm volatile("s_waitcnt vmcnt(6)" ::: "memory");
    __builtin_amdgcn_s_barrier();
    __builtin_amdgcn_sched_barrier(0);
    LOADF(aX, bX, 0);

#pragma unroll 1
    for (int it = 0; it < NI; ++it) {
        asm volatile("s_waitcnt lgkmcnt(0)" ::: "memory");
        __builtin_amdgcn_s_barrier();
        __builtin_amdgcn_sched_barrier(0);
        STAGE(0, 2 * it + 2);
        asm volatile("s_waitcnt vmcnt(6)" ::: "memory");
        __builtin_amdgcn_s_barrier();
        __builtin_amdgcn_sched_barrier(0);
        LOADF(aY, bY, 1);
        __builtin_amdgcn_s_setprio(1);
        MME(aX, bX);
        __builtin_amdgcn_s_setprio(0);
        asm volatile("s_waitcnt lgkmcnt(0)" ::: "memory");
        __builtin_amdgcn_s_barrier();
        __builtin_amdgcn_sched_barrier(0);
        STAGE(1, 2 * it + 3);
        asm volatile("s_waitcnt vmcnt(6)" ::: "memory");
        __builtin_amdgcn_s_barrier();
        __builtin_amdgcn_sched_barrier(0);
        LOADF(aX, bX, 0);
        __builtin_amdgcn_s_setprio(1);
        MME(aY, bY);
        __builtin_amdgcn_s_setprio(0);
    }

    asm volatile("s_waitcnt vmcnt(0) lgkmcnt(0)" ::: "memory");

    const int rq = (lane >> 4) << 2;
    const int er = m0 + wm * 64;
    const int ec = n0 + wn * 64 + am;
#pragma unroll
    for (int mi = 0; mi < 4; ++mi) {
#pragma unroll
        for (int nj = 0; nj < 4; ++nj) {
            int col = ec + nj * 16;
#pragma unroll
            for (int r = 0; r < 4; ++r) {
                int row = er + mi * 16 + rq + r;
                float v = acc[mi][nj][r];
                if (MODE == 0) {
                    out_bf[(size_t)row * DI + col] = f2b(v);
                } else if (MODE == 1) {
                    v += bias[col];
                    out_bf[(size_t)row * DI + col] = f2b(v);
                } else if (MODE == 2) {
                    v += bias[col];
                    float s = 1.f / (1.f + __expf(-v));
                    s = fminf(fmaxf(s, 1e-4f), 1.f);
                    out_bf[(size_t)row * DI + col] = f2b(s);
                } else { // MODE 4: Mbig[o][z*1024 + cm]
                    out_bf[(size_t)row * 4096 + (size_t)blockIdx.z * 1024 + col] = f2b(v);
                }
            }
        }
    }
}

// ---------------- B/C projection: MFMA split-K ----------------
__global__ void __launch_bounds__(256)
bc_mfma(const unsigned short* __restrict__ u,
        const unsigned short* __restrict__ w,
        float* __restrict__ pc)
{
    const int t = threadIdx.x;
    const int lane = t & 63;
    const int wave = t >> 6;
    const int ks = blockIdx.x;                    // 0..BCKS-1
    const int m0 = blockIdx.y * 128 + wave * 32;
    const int am = lane & 15, quad = lane >> 4;

    f32x4 acc[2][2];
#pragma unroll
    for (int i = 0; i < 2; ++i)
#pragma unroll
        for (int j = 0; j < 2; ++j)
            acc[i][j] = f32x4{0.f, 0.f, 0.f, 0.f};

    const int kbase = ks * (DI / BCKS);
    const unsigned short* ur0 = u + (size_t)(m0 + am) * DI;
    const unsigned short* ur1 = u + (size_t)(m0 + 16 + am) * DI;
    const unsigned short* wr0 = w + (size_t)am * DI;
    const unsigned short* wr1 = w + (size_t)(16 + am) * DI;
#pragma unroll 2
    for (int kk = 0; kk < DI / BCKS; kk += 32) {
        int k = kbase + kk + quad * 8;
        bf16x8 a0 = *(const bf16x8*)(ur0 + k);
        bf16x8 a1 = *(const bf16x8*)(ur1 + k);
        bf16x8 b0 = *(const bf16x8*)(wr0 + k);
        bf16x8 b1 = *(const bf16x8*)(wr1 + k);
        acc[0][0] = __builtin_amdgcn_mfma_f32_16x16x32_bf16(a0, b0, acc[0][0], 0, 0, 0);
        acc[0][1] = __builtin_amdgcn_mfma_f32_16x16x32_bf16(a0, b1, acc[0][1], 0, 0, 0);
        acc[1][0] = __builtin_amdgcn_mfma_f32_16x16x32_bf16(a1, b0, acc[1][0], 0, 0, 0);
        acc[1][1] = __builtin_amdgcn_mfma_f32_16x16x32_bf16(a1, b1, acc[1][1], 0, 0, 0);
    }
    float* base = pc + (size_t)ks * MTOT * 32;
#pragma unroll
    for (int i = 0; i < 2; ++i)
#pragma unroll
        for (int j = 0; j < 2; ++j)
#pragma unroll
            for (int r = 0; r < 4; ++r) {
                int row = m0 + i * 16 + quad * 4 + r;
                int col = j * 16 + am;
                base[(size_t)row * 32 + col] = acc[i][j][r];
            }
}

// ---------------- chunked selective scan (3 kernels, R5-proven) ----------
// scan_p1 reduces the bc split-K partials (pc) into LDS (bitwise the same
// ks-order sum as the old bc_reduce) and, from the dh==0 blocks, publishes
// the reduced bcf for scan_p3.
__global__ void __launch_bounds__(256)
scan_p1(const unsigned short* __restrict__ dt_bf,
        const unsigned short* __restrict__ u_bf,
        const float* __restrict__ pc,
        const float* __restrict__ A_log,
        float* __restrict__ Pbuf,
        float* __restrict__ Sb,
        float* __restrict__ bcf)
{
    const int t = threadIdx.x;
    const int blk = blockIdx.x;          // 1024 = c(64) x dh(8) x b(2)
    const int c  = blk & (NC - 1);
    const int dh = (blk >> 6) & 7;
    const int b  = blk >> 9;
    const int d  = dh * 256 + t;

    const size_t rowbase = (size_t)b * SEQL + (size_t)c * CL;

    __shared__ float sm[CL][32];
    for (int idx = t; idx < CL * 32; idx += 256) {
        int r = idx >> 5, n = idx & 31;
        size_t base = (rowbase + r) * 32 + n;
        float s = pc[base];
#pragma unroll
        for (int ks = 1; ks < BCKS; ++ks)
            s += pc[(size_t)ks * (MTOT * 32) + base];
        sm[r][n] = s;
        if (dh == 0) bcf[base] = s;
    }

    float Adn[16];
    {
        const float4* ar = (const float4*)(A_log + (size_t)d * DSN);
#pragma unroll
        for (int q = 0; q < 4; ++q) {
            float4 v = ar[q];
            Adn[q * 4 + 0] = -__expf(v.x);
            Adn[q * 4 + 1] = -__expf(v.y);
            Adn[q * 4 + 2] = -__expf(v.z);
            Adn[q * 4 + 3] = -__expf(v.w);
        }
    }
    float s[16], P[16];
#pragma unroll
    for (int n = 0; n < 16; ++n) { s[n] = 0.f; P[n] = 1.f; }

    __syncthreads();

    for (int l0 = 0; l0 < CL; l0 += 4) {
        float dt4[4], u4[4];
#pragma unroll
        for (int j = 0; j < 4; ++j) {
            size_t rb = rowbase + l0 + j;
            dt4[j] = b2f(dt_bf[rb * DI + d]);
            u4[j] = b2f(u_bf[rb * DI + d]);
        }
#pragma unroll
        for (int j = 0; j < 4; ++j) {
            const float4* Br = (const float4*)(&sm[l0 + j][0]);
            float Bn[16];
#pragma unroll
            for (int q = 0; q < 4; ++q) {
                float4 v = Br[q];
                Bn[q * 4 + 0] = v.x; Bn[q * 4 + 1] = v.y;
                Bn[q * 4 + 2] = v.z; Bn[q * 4 + 3] = v.w;
            }
            float dt = dt4[j];
            float dBu = dt * u4[j];
#pragma unroll
            for (int n = 0; n < 16; ++n) {
                float x = dt * Adn[n];
                x = fminf(fmaxf(x, -5.f), 5.f);
                float dA = __expf(x);
                P[n] *= dA;
                s[n] = dA * s[n] + (dBu * Bn[n] + 1e-6f);
            }
        }
    }
    size_t ob = (((size_t)c * BATCHN + b) * DI + d) * DSN;
#pragma unroll
    for (int q = 0; q < 4; ++q) {
        ((float4*)(Pbuf + ob))[q] = make_float4(P[q*4], P[q*4+1], P[q*4+2], P[q*4+3]);
        ((float4*)(Sb + ob))[q] = make_float4(s[q*4], s[q*4+1], s[q*4+2], s[q*4+3]);
    }
}

// scan_p2: chunk-prefix; Ibuf written IN PLACE over Sb (all 8 reads of a
// group precede the 8 writes at the same indices; later groups read chunks
// not yet written).
__global__ void __launch_bounds__(256)
scan_p2(const float* __restrict__ Pbuf,
        float* __restrict__ Sb)
{
    const int i = blockIdx.x * 256 + threadIdx.x;  // (b*DI+d)*16+n, 65536
    const int stride = BATCHN * DI * DSN;          // 65536
    float s = 0.f;
    for (int c0 = 0; c0 < NC; c0 += 8) {
        float Pv[8], Sv[8];
#pragma unroll
        for (int j = 0; j < 8; ++j) {
            size_t idx = (size_t)(c0 + j) * stride + i;
            Pv[j] = Pbuf[idx];
            Sv[j] = Sb[idx];
        }
#pragma unroll
        for (int j = 0; j < 8; ++j) {
            size_t idx = (size_t)(c0 + j) * stride + i;
            Sb[idx] = s;                           // Ibuf write (in place)
            s = Pv[j] * s + Sv[j];
        }
    }
}

__global__ void __launch_bounds__(256)
scan_p3(const unsigned short* __restrict__ dt_bf,
        const unsigned short* __restrict__ u_bf,
        const float* __restrict__ bcf,
        const unsigned short* __restrict__ z_bf,
        const float* __restrict__ A_log,
        const float* __restrict__ Dvec,
        const float* __restrict__ Ib,          // == Sb (prefix states)
        unsigned short* __restrict__ y_bf)
{
    const int t = threadIdx.x;
    const int blk = blockIdx.x;
    const int c  = blk & (NC - 1);
    const int dh = (blk >> 6) & 7;
    const int b  = blk >> 9;
    const int d  = dh * 256 + t;

    float Adn[16];
    {
        const float4* ar = (const float4*)(A_log + (size_t)d * DSN);
#pragma unroll
        for (int q = 0; q < 4; ++q) {
            float4 v = ar[q];
            Adn[q * 4 + 0] = -__expf(v.x);
            Adn[q * 4 + 1] = -__expf(v.y);
            Adn[q * 4 + 2] = -__expf(v.z);
            Adn[q * 4 + 3] = -__expf(v.w);
        }
    }
    const float Dd = Dvec[d];
    float s[16];
    {
        size_t ib = (((size_t)c * BATCHN + b) * DI + d) * DSN;
#pragma unroll
        for (int q = 0; q < 4; ++q) {
            float4 v = ((const float4*)(Ib + ib))[q];
            s[q * 4 + 0] = v.x; s[q * 4 + 1] = v.y;
            s[q * 4 + 2] = v.z; s[q * 4 + 3] = v.w;
        }
    }

    const size_t rowbase = (size_t)b * SEQL + (size_t)c * CL;
    for (int l0 = 0; l0 < CL; l0 += 4) {
        float dt4[4], u4[4], z4[4];
#pragma unroll
        for (int j = 0; j < 4; ++j) {
            size_t rb = rowbase + l0 + j;
            dt4[j] = b2f(dt_bf[rb * DI + d]);
            u4[j] = b2f(u_bf[rb * DI + d]);
            z4[j] = b2f(z_bf[rb * DI + d]);
        }
#pragma unroll
        for (int j = 0; j < 4; ++j) {
            size_t rb = rowbase + l0 + j;
            const float4* Br = (const float4*)(bcf + rb * 32);
            float Bn[16], Cn[16];
#pragma unroll
            for (int q = 0; q < 4; ++q) {
                float4 v = Br[q];
                Bn[q * 4 + 0] = v.x; Bn[q * 4 + 1] = v.y;
                Bn[q * 4 + 2] = v.z; Bn[q * 4 + 3] = v.w;
                float4 w = Br[q + 4];
                Cn[q * 4 + 0] = w.x; Cn[q * 4 + 1] = w.y;
                Cn[q * 4 + 2] = w.z; Cn[q * 4 + 3] = w.w;
            }
            float dt = dt4[j];
            float dBu = dt * u4[j];
            float y = 0.f;
#pragma unroll
            for (int n = 0; n < 16; ++n) {
                float x = dt * Adn[n];
                x = fminf(fmaxf(x, -5.f), 5.f);
                float dA = __expf(x);
                s[n] = dA * s[n] + (dBu * Bn[n] + 1e-6f);
                y += s[n] * Cn[n];
            }
            y += Dd * u4[j];
            float zz = z4[j];
            y *= zz / (1.f + __expf(-zz));
            y_bf[rb * DI + d] = f2b(y);
        }
    }
}

// ---------------- launch ----------------
// R7 overlay (dispatch order: 1.cvt 2.mk 3.z 4.conv 5.bc 6.dt 7.p1 8.p2 9.p3 10.out).
// Per-slot lifetimes (w:writer dispatch, r:reader dispatches):
//   S1 [0,33.55M):  wk(w:1,r:2) -> dt_bf[0,16.78M)(w:6,r:7,9)
//                              -> Pbuf[16.78,33.55M)(w:7,r:8) -> y_bf same(w:9,r:10)
//   S2 [33.55,50.33M): mk(w:2,r:4) -> Sb==Sbuf/Ibuf(w:7,rw:8,r:9)
//   S3 [50.33,58.73M): xpad(w:1,r:3,4) -> pc[50.33,54.53M)(w:5,r:7)
//   S4 [58.73,75.51M): z_bf(w:3,r:9) with Pt(w:1,r:2) aliased in first 4.2M
//   S5 ipz(w:1,r:3)  S6 dtw(w:1,r:6)  S7 ow(w:1,r:10)  S8 bc_bf(w:1,r:5)
//   S9 bcf(w:7,r:9)  S10 u_bf(w:4,r:5,6,7,9)
// Total ws = 109,719,552 bytes (R5: 131.5 MB).
extern "C" void kernel_launch(void* const* d_in, const int* in_sizes, int n_in,
                              void* d_out, int out_size, void* d_ws, size_t ws_size,
                              hipStream_t stream) {
    const float* x     = (const float*)d_in[0];
    const float* ipw   = (const float*)d_in[1];
    const float* convw = (const float*)d_in[2];
    const float* convb = (const float*)d_in[3];
    const float* dtw   = (const float*)d_in[4];
    const float* dtb   = (const float*)d_in[5];
    const float* alog  = (const float*)d_in[6];
    const float* dvec  = (const float*)d_in[7];
    const float* bw    = (const float*)d_in[8];
    const float* cwm   = (const float*)d_in[9];
    const float* ow    = (const float*)d_in[10];
    float* out = (float*)d_out;

    char* ws = (char*)d_ws;
    unsigned short* wk_bf  = (unsigned short*)(ws);                // S1
    unsigned short* dt_bf  = (unsigned short*)(ws);                //   [0,16.78M)
    float*          Pbuf   = (float*)(ws + 16777216);              //   [16.78M,33.55M)
    unsigned short* y_bf   = (unsigned short*)(ws + 16777216);     //   same slot
    unsigned short* mk_bf  = (unsigned short*)(ws + 33554432);     // S2
    float*          Sb     = (float*)(ws + 33554432);              //   Sbuf==Ibuf
    unsigned short* xpad   = (unsigned short*)(ws + 50331648);     // S3
    float*          pc_f   = (float*)(ws + 50331648);
    unsigned short* z_bf   = (unsigned short*)(ws + 58732544);     // S4 (16.78M)
    unsigned short* Pt_bf  = (unsigned short*)(ws + 58732544);     //   aliased, dead@2
    unsigned short* ipz_bf = (unsigned short*)(ws + 75509760);     // S5 (4.19M)
    unsigned short* dtw_bf = (unsigned short*)(ws + 79704064);     // S6 (8.39M)
    unsigned short* ow_bf  = (unsigned short*)(ws + 88092672);     // S7 (4.19M)
    unsigned short* bc_bf  = (unsigned short*)(ws + 92286976);     // S8 (131K)
    float*          bc_f   = (float*)(ws + 92418048);              // S9 (524K)
    unsigned short* u_bf   = (unsigned short*)(ws + 92942336);     // S10 (16.78M)
    // total 109,719,552 bytes

    // all converts in one launch
    cvt_all<<<NB_CVT_ALL, 256, 0, stream>>>(x, convw, ipw, dtw, ow, bw, cwm,
                                            xpad, wk_bf, Pt_bf, ipz_bf, dtw_bf,
                                            ow_bf, bc_bf);

    // mk-fuse: Mbig[o][z*1024+cm] = (W_z @ P)[o][cm]
    gemm8<4><<<dim3(8, 8, 4), 512, 0, stream>>>(wk_bf, Pt_bf, nullptr, mk_bf, nullptr);
    // z-proj: z = x @ ipz^T  (writes z_bf, overwriting dead Pt alias)
    gemm8<0><<<dim3(16, 16), 512, 0, stream>>>(xpad, ipz_bf, nullptr, z_bf, nullptr);
    // conv (fused, single K=4096 GEMM over xpad sliding window x Mbig^T)
    gemm8<1><<<dim3(16, 16), 512, 0, stream>>>(xpad, mk_bf, convb, u_bf, nullptr);
    // B/C projection: MFMA split-K (reduce fused into scan_p1)
    bc_mfma<<<dim3(BCKS, MTOT / 128), 256, 0, stream>>>(u_bf, bc_bf, pc_f);
    // dt projection + sigmoid/clip -> bf16
    gemm8<2><<<dim3(16, 16), 512, 0, stream>>>(u_bf, dtw_bf, dtb, dt_bf, nullptr);
    // chunked scan: p1 (local scan + pc reduce + bcf publish), p2 (prefix,
    // in-place Ibuf over Sb), p3 (rescan, y)
    scan_p1<<<BATCHN * 8 * NC, 256, 0, stream>>>(dt_bf, u_bf, pc_f, alog, Pbuf, Sb, bc_f);
    scan_p2<<<BATCHN * DI * DSN / 256, 256, 0, stream>>>(Pbuf, Sb);
    scan_p3<<<BATCHN * 8 * NC, 256, 0, stream>>>(dt_bf, u_bf, bc_f, z_bf, alog, dvec, Sb, y_bf);
    // out projection
    gemm_bt<3><<<dim3(8, 32), 256, 0, stream>>>(y_bf, ow_bf, nullptr, nullptr, out, DI);
}